// Round 3
// baseline (291.401 us; speedup 1.0000x reference)
//
#include <hip/hip_runtime.h>

// Full 2D convolution: in (32,16,256,256) f32, shared 5x5 kernel, out (32,16,260,260) f32.
// out[n][y][x] = sum_{a,b in [0,5)} in[n][y-a][x-b] * w[a][b]
//
// R4c: second resubmit of the R4 experiment (rounds 1-2 died to container infra
// failures with no signal; kernel audited clean). Lambda flattened to straight-line
// code as a de-risking cleanup -- zero semantic change.
//
//  - Weights forced into SGPRs (readfirstlane): wave-uniform; frees 25 VGPRs.
//  - 4-row x 4-wide output strip per thread, STREAMING: 8 input rows consumed
//    one-by-one (3 rows in flight) and FMA'd directly into 16 accumulators as
//    they arrive. No 14-row window buffer -> live VGPRs ~50.
//  - __launch_bounds__(256, 8): pin allocator to the <=64-VGPR granule -> 8
//    waves/SIMD cap (R3's 76 regs burned a 128-reg granule -> 4 waves/SIMD;
//    measured VALUBusy==Occupancy==27%, i.e. pure residency shortage).
//  - Branch-free edges: clamped always-valid 16B loads + cndmask zeroing.

#define IMG 256
#define OW  260
#define TXN 65            // float4s per output row
#define ROWS 4            // output rows per thread
#define IROWS 8           // input rows touched: ROWS + 4
#define STRIPS 65         // 260 / 4
#define NIMG 512          // 32*16 images
#define NTHREADS (NIMG * STRIPS * TXN)   // 512*65*65 = 2,163,200 = 8450 * 256

#define ISSUE(rr)                                                         \
    {                                                                     \
        int yy = y0 + (rr) - 4;                                           \
        int yc = yy < 0 ? 0 : (yy > IMG - 1 ? IMG - 1 : yy);              \
        const float* rb = img + yc * IMG;                                 \
        rawL[rr] = *(const float4*)(rb + xl);                             \
        rawH[rr] = *(const float4*)(rb + xh);                             \
    }

__global__ __launch_bounds__(256, 8) void conv_full_stream4(
    const float* __restrict__ in, const float* __restrict__ w,
    float* __restrict__ out)
{
    // ---- Weights: wave-uniform -> force into SGPRs.
    float wt[25];
#pragma unroll
    for (int i = 0; i < 25; ++i)
        wt[i] = __int_as_float(__builtin_amdgcn_readfirstlane(__float_as_int(w[i])));

    int idx = blockIdx.x * 256 + threadIdx.x;
    int tx4 = idx % TXN;
    int t   = idx / TXN;
    int s   = t % STRIPS;
    int n   = t / STRIPS;
    int y0  = s * ROWS;
    int x0  = tx4 * 4;

    // Clamped, always-in-bounds 16B-aligned load columns.
    int xl = x0 - 4; if (xl < 0) xl = 0;
    int xh = x0;     if (xh > IMG - 4) xh = IMG - 4;
    const bool zL = (tx4 == 0);         // cols x0-4..x0-1 left of image
    const bool zR = (tx4 == TXN - 1);   // cols 256..259 right of image

    const float* img = in + (size_t)n * (IMG * IMG);

    float4 rawL[IROWS], rawH[IROWS];

    // Prefetch 3 rows (6 loads in flight max).
    ISSUE(0); ISSUE(1); ISSUE(2);

    float acc[ROWS][4];
#pragma unroll
    for (int r = 0; r < ROWS; ++r)
        acc[r][0] = acc[r][1] = acc[r][2] = acc[r][3] = 0.f;

#pragma unroll
    for (int rr = 0; rr < IROWS; ++rr) {
        if (rr + 3 < IROWS) ISSUE(rr + 3);   // keep 3 rows in flight

        // Branch-free masking of this input row into an 8-wide window.
        int yy = y0 + rr - 4;
        bool rv = (yy >= 0) & (yy < IMG);
        bool mL = rv & !zL;
        bool mR = rv & !zR;
        float v[8];
        v[0] = mL ? rawL[rr].x : 0.f;
        v[1] = mL ? rawL[rr].y : 0.f;
        v[2] = mL ? rawL[rr].z : 0.f;
        v[3] = mL ? rawL[rr].w : 0.f;
        v[4] = mR ? rawH[rr].x : 0.f;
        v[5] = mR ? rawH[rr].y : 0.f;
        v[6] = mR ? rawH[rr].z : 0.f;
        v[7] = mR ? rawH[rr].w : 0.f;

        // Input row y0+rr-4 feeds output rows r with a = r-rr+4 in [0,4].
#pragma unroll
        for (int r = 0; r < ROWS; ++r) {
            const int a = r - rr + 4;
            if (a >= 0 && a <= 4) {
#pragma unroll
                for (int b = 0; b < 5; ++b) {
                    float wv = wt[a * 5 + b];
                    acc[r][0] = fmaf(v[4 - b], wv, acc[r][0]);
                    acc[r][1] = fmaf(v[5 - b], wv, acc[r][1]);
                    acc[r][2] = fmaf(v[6 - b], wv, acc[r][2]);
                    acc[r][3] = fmaf(v[7 - b], wv, acc[r][3]);
                }
            }
        }
    }

    // ---- Store 4 output rows, one float4 each.
    float* outp = out + (((size_t)n * OW + y0) * TXN + tx4) * 4;
#pragma unroll
    for (int r = 0; r < ROWS; ++r)
        *(float4*)(outp + (size_t)r * OW) =
            make_float4(acc[r][0], acc[r][1], acc[r][2], acc[r][3]);
}

extern "C" void kernel_launch(void* const* d_in, const int* in_sizes, int n_in,
                              void* d_out, int out_size, void* d_ws, size_t ws_size,
                              hipStream_t stream) {
    const float* in = (const float*)d_in[0];   // 32*16*256*256 f32
    const float* w  = (const float*)d_in[1];   // 5*5 f32
    float* out = (float*)d_out;                // 32*16*260*260 f32

    int blocks = NTHREADS / 256;               // exactly 8450
    conv_full_stream4<<<blocks, 256, 0, stream>>>(in, w, out);
}

// Round 5
// 255.928 us; speedup vs baseline: 1.1386x; 1.1386x over previous
//
#include <hip/hip_runtime.h>

// Full 2D convolution: in (32,16,256,256) f32, shared 5x5 kernel, out (32,16,260,260) f32.
// out[n][y][x] = sum_{a,b in [0,5)} in[n][y-a][x-b] * w[a][b]
//
// R5b: resubmit of R5 (round-4 bench died to a harness-side Trio nursery
// exception; no kernel signal). Merge of the two separately-verified wins:
//  - R4c proved occupancy is VGPR-step-limited and recoverable (27%->80%), but
//    __launch_bounds__(256,8) squeezed the allocator to a 32-reg cap (empirical
//    hipcc mapping ~ 256/arg2, NOT 512/arg2) -> scratch spill -> +380 MB HBM
//    traffic (WRITE 137k->323k KB) -> regression. R3 proved the clean-traffic
//    structure (WRITE exactly 137k KB, FETCH 75k KB, zero scratch).
//  - R5: streaming ROWS=10 strip. Per input row (14 total): load 2 clamped
//    float4s, mask in place, FMA into the <=5 output-row accumulators it feeds.
//    Live state = acc[10][4] (40) + 1 row in flight (8) + addressing (~10)
//    ~= 58 VGPRs -- under the 64-reg occupancy step BY DESIGN, so 8 waves/SIMD
//    without coercing the allocator.
//  - Weights in SGPRs via readfirstlane (wave-uniform; frees 25 VGPRs).
//  - __launch_bounds__(256,4): cap 64 under the empirical mapping, 128 under
//    the documented one -- both >= demand, spill impossible.
//  - Latency hiding from TLP (8 waves/SIMD), not deep ILP pipelines.
//  - Edge handling identical to R3/R4 (verified twice): clamped always-in-bounds
//    16B loads + branch-free cndmask zeroing of out-of-image rows/columns.

#define IMG 256
#define OW  260
#define TXN 65            // float4s per output row
#define ROWS 10           // output rows per thread
#define IROWS 14          // input rows touched: ROWS + 4
#define STRIPS 26         // 260 / 10
#define NIMG 512          // 32*16 images
#define NTHREADS (NIMG * STRIPS * TXN)   // 865,280 = 3380 * 256

__global__ __launch_bounds__(256, 4) void conv_full_stream5(
    const float* __restrict__ in, const float* __restrict__ w,
    float* __restrict__ out)
{
    // ---- Weights: wave-uniform -> force into SGPRs.
    float wt[25];
#pragma unroll
    for (int i = 0; i < 25; ++i)
        wt[i] = __int_as_float(__builtin_amdgcn_readfirstlane(__float_as_int(w[i])));

    int idx = blockIdx.x * 256 + threadIdx.x;
    int tx4 = idx % TXN;
    int t   = idx / TXN;
    int s   = t % STRIPS;
    int n   = t / STRIPS;
    int y0  = s * ROWS;
    int x0  = tx4 * 4;

    // Clamped, always-in-bounds 16B-aligned load columns.
    int xl = x0 - 4; if (xl < 0) xl = 0;
    int xh = x0;     if (xh > IMG - 4) xh = IMG - 4;
    const bool zL = (tx4 == 0);         // cols x0-4..x0-1 left of image
    const bool zR = (tx4 == TXN - 1);   // cols 256..259 right of image

    const float* img = in + (size_t)n * (IMG * IMG);

    float acc[ROWS][4];
#pragma unroll
    for (int r = 0; r < ROWS; ++r)
        acc[r][0] = acc[r][1] = acc[r][2] = acc[r][3] = 0.f;

    // ---- Stream 14 input rows; consume each immediately (1 row of live state).
#pragma unroll
    for (int rr = 0; rr < IROWS; ++rr) {
        int yy = y0 + rr - 4;
        int yc = yy < 0 ? 0 : (yy > IMG - 1 ? IMG - 1 : yy);
        const float* rb = img + yc * IMG;
        float4 rl = *(const float4*)(rb + xl);
        float4 rh = *(const float4*)(rb + xh);

        bool rv = (yy >= 0) & (yy < IMG);
        bool mL = rv & !zL;
        bool mR = rv & !zR;
        float v0 = mL ? rl.x : 0.f;
        float v1 = mL ? rl.y : 0.f;
        float v2 = mL ? rl.z : 0.f;
        float v3 = mL ? rl.w : 0.f;
        float v4 = mR ? rh.x : 0.f;
        float v5 = mR ? rh.y : 0.f;
        float v6 = mR ? rh.z : 0.f;
        float v7 = mR ? rh.w : 0.f;
        float v[8] = {v0, v1, v2, v3, v4, v5, v6, v7};

        // Input row y0+rr-4 feeds output rows r with a = r-rr+4 in [0,4].
#pragma unroll
        for (int r = 0; r < ROWS; ++r) {
            const int a = r - rr + 4;
            if (a >= 0 && a <= 4) {
#pragma unroll
                for (int b = 0; b < 5; ++b) {
                    float wv = wt[a * 5 + b];
                    acc[r][0] = fmaf(v[4 - b], wv, acc[r][0]);
                    acc[r][1] = fmaf(v[5 - b], wv, acc[r][1]);
                    acc[r][2] = fmaf(v[6 - b], wv, acc[r][2]);
                    acc[r][3] = fmaf(v[7 - b], wv, acc[r][3]);
                }
            }
        }
    }

    // ---- Store 10 output rows, one float4 each.
    float* outp = out + (((size_t)n * OW + y0) * TXN + tx4) * 4;
#pragma unroll
    for (int r = 0; r < ROWS; ++r)
        *(float4*)(outp + (size_t)r * OW) =
            make_float4(acc[r][0], acc[r][1], acc[r][2], acc[r][3]);
}

extern "C" void kernel_launch(void* const* d_in, const int* in_sizes, int n_in,
                              void* d_out, int out_size, void* d_ws, size_t ws_size,
                              hipStream_t stream) {
    const float* in = (const float*)d_in[0];   // 32*16*256*256 f32
    const float* w  = (const float*)d_in[1];   // 5*5 f32
    float* out = (float*)d_out;                // 32*16*260*260 f32

    int blocks = NTHREADS / 256;               // exactly 3380
    conv_full_stream5<<<blocks, 256, 0, stream>>>(in, w, out);
}

// Round 6
// 243.406 us; speedup vs baseline: 1.1972x; 1.0514x over previous
//
#include <hip/hip_runtime.h>

// Full 2D convolution: in (32,16,256,256) f32, shared 5x5 kernel, out (32,16,260,260) f32.
// out[n][y][x] = sum_{a,b in [0,5)} in[n][y-a][x-b] * w[a][b]
//
// R6: single-variable change from R5b: ROWS 10 -> 5.
//  - R5b evidence: VGPR_Count == 64 EXACTLY (the (256,4) cap binding) + WRITE
//    inflated 137k->185k KB + FETCH 75k->105k KB => small scratch spill. True
//    demand at ROWS=10 was ~70-76 (compiler pipelines next-row loads), not ~58.
//    Occupancy did rise (27->36%) and time improved 97->90.8 us, so the
//    residency lever is real; the spill is what's capping it.
//  - ROWS=5 demand: acc[5][4]=20 + row in flight (8) + pipelined next row (8)
//    + addressing (~12) ~= 48-54 regs, comfortably under the 64 cap -> spill
//    impossible by design, 8 waves/SIMD.
//  - Halo redundancy rises to 9/5=1.8x, but R3/R5b proved input (134 MB) lives
//    in the 256 MB L3 (R3 FETCH was 77 MB < input), so re-reads don't touch HBM.
//  - Grid 6760 blocks = 27k waves -> 3.3 residency rounds, smaller tail.
//  - Weights in SGPRs via readfirstlane; edge handling identical to the
//    twice-verified clamped-load + cndmask scheme.

#define IMG 256
#define OW  260
#define TXN 65            // float4s per output row
#define ROWS 5            // output rows per thread
#define IROWS 9           // input rows touched: ROWS + 4
#define STRIPS 52         // 260 / 5
#define NIMG 512          // 32*16 images
#define NTHREADS (NIMG * STRIPS * TXN)   // 512*52*65 = 1,730,560 = 6760 * 256

__global__ __launch_bounds__(256, 4) void conv_full_stream6(
    const float* __restrict__ in, const float* __restrict__ w,
    float* __restrict__ out)
{
    // ---- Weights: wave-uniform -> force into SGPRs.
    float wt[25];
#pragma unroll
    for (int i = 0; i < 25; ++i)
        wt[i] = __int_as_float(__builtin_amdgcn_readfirstlane(__float_as_int(w[i])));

    int idx = blockIdx.x * 256 + threadIdx.x;
    int tx4 = idx % TXN;
    int t   = idx / TXN;
    int s   = t % STRIPS;
    int n   = t / STRIPS;
    int y0  = s * ROWS;
    int x0  = tx4 * 4;

    // Clamped, always-in-bounds 16B-aligned load columns.
    int xl = x0 - 4; if (xl < 0) xl = 0;
    int xh = x0;     if (xh > IMG - 4) xh = IMG - 4;
    const bool zL = (tx4 == 0);         // cols x0-4..x0-1 left of image
    const bool zR = (tx4 == TXN - 1);   // cols 256..259 right of image

    const float* img = in + (size_t)n * (IMG * IMG);

    float acc[ROWS][4];
#pragma unroll
    for (int r = 0; r < ROWS; ++r)
        acc[r][0] = acc[r][1] = acc[r][2] = acc[r][3] = 0.f;

    // ---- Stream 9 input rows; consume each immediately (1 row of live state).
#pragma unroll
    for (int rr = 0; rr < IROWS; ++rr) {
        int yy = y0 + rr - 4;
        int yc = yy < 0 ? 0 : (yy > IMG - 1 ? IMG - 1 : yy);
        const float* rb = img + yc * IMG;
        float4 rl = *(const float4*)(rb + xl);
        float4 rh = *(const float4*)(rb + xh);

        bool rv = (yy >= 0) & (yy < IMG);
        bool mL = rv & !zL;
        bool mR = rv & !zR;
        float v[8];
        v[0] = mL ? rl.x : 0.f;
        v[1] = mL ? rl.y : 0.f;
        v[2] = mL ? rl.z : 0.f;
        v[3] = mL ? rl.w : 0.f;
        v[4] = mR ? rh.x : 0.f;
        v[5] = mR ? rh.y : 0.f;
        v[6] = mR ? rh.z : 0.f;
        v[7] = mR ? rh.w : 0.f;

        // Input row y0+rr-4 feeds output rows r with a = r-rr+4 in [0,4].
#pragma unroll
        for (int r = 0; r < ROWS; ++r) {
            const int a = r - rr + 4;
            if (a >= 0 && a <= 4) {
#pragma unroll
                for (int b = 0; b < 5; ++b) {
                    float wv = wt[a * 5 + b];
                    acc[r][0] = fmaf(v[4 - b], wv, acc[r][0]);
                    acc[r][1] = fmaf(v[5 - b], wv, acc[r][1]);
                    acc[r][2] = fmaf(v[6 - b], wv, acc[r][2]);
                    acc[r][3] = fmaf(v[7 - b], wv, acc[r][3]);
                }
            }
        }
    }

    // ---- Store 5 output rows, one float4 each.
    float* outp = out + (((size_t)n * OW + y0) * TXN + tx4) * 4;
#pragma unroll
    for (int r = 0; r < ROWS; ++r)
        *(float4*)(outp + (size_t)r * OW) =
            make_float4(acc[r][0], acc[r][1], acc[r][2], acc[r][3]);
}

extern "C" void kernel_launch(void* const* d_in, const int* in_sizes, int n_in,
                              void* d_out, int out_size, void* d_ws, size_t ws_size,
                              hipStream_t stream) {
    const float* in = (const float*)d_in[0];   // 32*16*256*256 f32
    const float* w  = (const float*)d_in[1];   // 5*5 f32
    float* out = (float*)d_out;                // 32*16*260*260 f32

    int blocks = NTHREADS / 256;               // exactly 6760
    conv_full_stream6<<<blocks, 256, 0, stream>>>(in, w, out);
}

// Round 8
// 242.736 us; speedup vs baseline: 1.2005x; 1.0028x over previous
//
#include <hip/hip_runtime.h>

// Full 2D convolution: in (32,16,256,256) f32, shared 5x5 kernel, out (32,16,260,260) f32.
// out[n][y][x] = sum_{a,b in [0,5)} in[n][y-a][x-b] * w[a][b]
//
// R7b: fix of R7's compile error. __builtin_nontemporal_store rejects HIP's
// float4 (a HIP_vector_type class); it wants a clang vector type. Store through
// a native ext_vector_type(4) float alias instead -- same 16B dwordx4 store,
// now with the nt (evict-first) flag. Theory unchanged:
//  - R6 status: ROWS=5, no spill, kernel ~79 us (below the 88-us harness fills).
//  - Working set 134 MB in + 138 MB out = 272 MB > 256 MB L3 -> write stream
//    evicts input lines -> R5b measured FETCH ~105 MB re-fetched per pass,
//    ~3.3 TB/s effective while fillBuffer proves 6.24 TB/s available.
//  - Output is write-once/never-read: nt stores keep L3 for the input.
//    Predicted: FETCH <40k KB, WRITE unchanged ~137k KB, kernel ~55-65 us.
//  - Everything else identical to R6 (verified): ROWS=5 streaming strip,
//    weights in SGPRs via readfirstlane, clamped-load + cndmask edges,
//    __launch_bounds__(256,4).

#define IMG 256
#define OW  260
#define TXN 65            // float4s per output row
#define ROWS 5            // output rows per thread
#define IROWS 9           // input rows touched: ROWS + 4
#define STRIPS 52         // 260 / 5
#define NIMG 512          // 32*16 images
#define NTHREADS (NIMG * STRIPS * TXN)   // 512*52*65 = 1,730,560 = 6760 * 256

typedef float f32x4 __attribute__((ext_vector_type(4)));

__global__ __launch_bounds__(256, 4) void conv_full_stream7b(
    const float* __restrict__ in, const float* __restrict__ w,
    float* __restrict__ out)
{
    // ---- Weights: wave-uniform -> force into SGPRs.
    float wt[25];
#pragma unroll
    for (int i = 0; i < 25; ++i)
        wt[i] = __int_as_float(__builtin_amdgcn_readfirstlane(__float_as_int(w[i])));

    int idx = blockIdx.x * 256 + threadIdx.x;
    int tx4 = idx % TXN;
    int t   = idx / TXN;
    int s   = t % STRIPS;
    int n   = t / STRIPS;
    int y0  = s * ROWS;
    int x0  = tx4 * 4;

    // Clamped, always-in-bounds 16B-aligned load columns.
    int xl = x0 - 4; if (xl < 0) xl = 0;
    int xh = x0;     if (xh > IMG - 4) xh = IMG - 4;
    const bool zL = (tx4 == 0);         // cols x0-4..x0-1 left of image
    const bool zR = (tx4 == TXN - 1);   // cols 256..259 right of image

    const float* img = in + (size_t)n * (IMG * IMG);

    float acc[ROWS][4];
#pragma unroll
    for (int r = 0; r < ROWS; ++r)
        acc[r][0] = acc[r][1] = acc[r][2] = acc[r][3] = 0.f;

    // ---- Stream 9 input rows; consume each immediately (1 row of live state).
#pragma unroll
    for (int rr = 0; rr < IROWS; ++rr) {
        int yy = y0 + rr - 4;
        int yc = yy < 0 ? 0 : (yy > IMG - 1 ? IMG - 1 : yy);
        const float* rb = img + yc * IMG;
        float4 rl = *(const float4*)(rb + xl);
        float4 rh = *(const float4*)(rb + xh);

        bool rv = (yy >= 0) & (yy < IMG);
        bool mL = rv & !zL;
        bool mR = rv & !zR;
        float v[8];
        v[0] = mL ? rl.x : 0.f;
        v[1] = mL ? rl.y : 0.f;
        v[2] = mL ? rl.z : 0.f;
        v[3] = mL ? rl.w : 0.f;
        v[4] = mR ? rh.x : 0.f;
        v[5] = mR ? rh.y : 0.f;
        v[6] = mR ? rh.z : 0.f;
        v[7] = mR ? rh.w : 0.f;

        // Input row y0+rr-4 feeds output rows r with a = r-rr+4 in [0,4].
#pragma unroll
        for (int r = 0; r < ROWS; ++r) {
            const int a = r - rr + 4;
            if (a >= 0 && a <= 4) {
#pragma unroll
                for (int b = 0; b < 5; ++b) {
                    float wv = wt[a * 5 + b];
                    acc[r][0] = fmaf(v[4 - b], wv, acc[r][0]);
                    acc[r][1] = fmaf(v[5 - b], wv, acc[r][1]);
                    acc[r][2] = fmaf(v[6 - b], wv, acc[r][2]);
                    acc[r][3] = fmaf(v[7 - b], wv, acc[r][3]);
                }
            }
        }
    }

    // ---- Store 5 output rows, one non-temporal 16B store each (evict-first:
    // output is write-once, keep L3 for the input).
    float* outp = out + (((size_t)n * OW + y0) * TXN + tx4) * 4;
#pragma unroll
    for (int r = 0; r < ROWS; ++r) {
        f32x4 val = { acc[r][0], acc[r][1], acc[r][2], acc[r][3] };
        __builtin_nontemporal_store(val, (f32x4*)(outp + (size_t)r * OW));
    }
}

extern "C" void kernel_launch(void* const* d_in, const int* in_sizes, int n_in,
                              void* d_out, int out_size, void* d_ws, size_t ws_size,
                              hipStream_t stream) {
    const float* in = (const float*)d_in[0];   // 32*16*256*256 f32
    const float* w  = (const float*)d_in[1];   // 5*5 f32
    float* out = (float*)d_out;                // 32*16*260*260 f32

    int blocks = NTHREADS / 256;               // exactly 6760
    conv_full_stream7b<<<blocks, 256, 0, stream>>>(in, w, out);
}